// Round 5
// baseline (224.195 us; speedup 1.0000x reference)
//
#include <hip/hip_runtime.h>
#include <hip/hip_bf16.h>
#include <stdint.h>

#define B_ 8
#define N_ 2048
#define D_ 256
#define BN (B_*N_)
#define NSEG 64
#define SROWS (N_/NSEG)   // 32 rows per segment

typedef __bf16 bf16;
typedef bf16 bf16x8 __attribute__((ext_vector_type(8)));
typedef bf16 bf16x4 __attribute__((ext_vector_type(4)));
typedef float f32x4 __attribute__((ext_vector_type(4)));

// ---- kernel 0: transpose weights to bf16 [d][k] ----
__global__ __launch_bounds__(256) void k_transpose_w(
    const float* __restrict__ w, const float* __restrict__ hw,
    bf16* __restrict__ wt, bf16* __restrict__ hwt) {
  int t = blockIdx.x * 256 + threadIdx.x;   // 65536 total
  int d = t >> 8, k = t & 255;
  wt[t]  = (bf16)w[k * D_ + d];
  hwt[t] = (bf16)hw[k * D_ + d];
}

// ---- kernel 1: h^T = (x@W)^T in bf16 (MFMA), fused with a1/a2 row stats ----
__global__ __launch_bounds__(256) void k_gemm_h(
    const float* __restrict__ x, const bf16* __restrict__ wt,
    const float* __restrict__ avec, bf16* __restrict__ hT,
    float* __restrict__ a1, float* __restrict__ e1, float* __restrict__ f1,
    float* __restrict__ a2, float* __restrict__ e2, float* __restrict__ f2) {
  int blk = blockIdx.x;            // 256 blocks
  int b = blk >> 5;
  int j0 = (blk & 31) * 64;
  int w = threadIdx.x >> 6, l = threadIdx.x & 63;
  int jr = j0 + w * 16 + (l & 15);
  const float* xrow = x + ((size_t)(b * N_ + jr)) * D_;
  int koff = 8 * (l >> 4);
  f32x4 acc[16];
  #pragma unroll
  for (int i = 0; i < 16; ++i) acc[i] = f32x4{0.f, 0.f, 0.f, 0.f};
  float s1 = 0.f, s2 = 0.f;
  for (int kb = 0; kb < D_; kb += 32) {
    float4 xa = *(const float4*)(xrow + kb + koff);
    float4 xb = *(const float4*)(xrow + kb + koff + 4);
    float4 ua = *(const float4*)(avec + kb + koff);
    float4 ub = *(const float4*)(avec + kb + koff + 4);
    float4 va = *(const float4*)(avec + D_ + kb + koff);
    float4 vb = *(const float4*)(avec + D_ + kb + koff + 4);
    s1 = fmaf(xa.x, ua.x, fmaf(xa.y, ua.y, fmaf(xa.z, ua.z, fmaf(xa.w, ua.w, s1))));
    s1 = fmaf(xb.x, ub.x, fmaf(xb.y, ub.y, fmaf(xb.z, ub.z, fmaf(xb.w, ub.w, s1))));
    s2 = fmaf(xa.x, va.x, fmaf(xa.y, va.y, fmaf(xa.z, va.z, fmaf(xa.w, va.w, s2))));
    s2 = fmaf(xb.x, vb.x, fmaf(xb.y, vb.y, fmaf(xb.z, vb.z, fmaf(xb.w, vb.w, s2))));
    bf16x8 af = { (bf16)xa.x, (bf16)xa.y, (bf16)xa.z, (bf16)xa.w,
                  (bf16)xb.x, (bf16)xb.y, (bf16)xb.z, (bf16)xb.w };
    #pragma unroll
    for (int dt = 0; dt < 16; ++dt) {
      bf16x8 bfr = *(const bf16x8*)(wt + (dt * 16 + (l & 15)) * D_ + kb + koff);
      acc[dt] = __builtin_amdgcn_mfma_f32_16x16x32_bf16(af, bfr, acc[dt], 0, 0, 0);
    }
  }
  // row-stat reduction: lanes l, l^16, l^32, l^48 share row jr
  s1 += __shfl_xor(s1, 16); s1 += __shfl_xor(s1, 32);
  s2 += __shfl_xor(s2, 16); s2 += __shfl_xor(s2, 32);
  if (l < 16) {
    int row = b * N_ + j0 + w * 16 + l;
    a1[row] = s1; e1[row] = __expf(s1); f1[row] = __expf(0.2f * s1);
    a2[row] = s2; e2[row] = __expf(s2); f2[row] = __expf(0.2f * s2);
  }
  int jw = j0 + w * 16 + (l >> 4) * 4;
  #pragma unroll
  for (int dt = 0; dt < 16; ++dt) {
    int d = dt * 16 + (l & 15);
    bf16x4 o = { (bf16)acc[dt][0], (bf16)acc[dt][1], (bf16)acc[dt][2], (bf16)acc[dt][3] };
    *(bf16x4*)(hT + ((size_t)(b * D_ + d)) * N_ + jw) = o;   // hT[b][d][j]
  }
}

// ---- kernel 2: column partial sums + adj->bitmask (vectorized, ballot-free) ----
__global__ __launch_bounds__(256) void k_colstats(
    const int* __restrict__ adj,
    const float* __restrict__ a1, const float* __restrict__ e1, const float* __restrict__ f1,
    const float* __restrict__ a2,
    float* __restrict__ partA, float* __restrict__ partB,
    unsigned char* __restrict__ maskB) {
  int blk = blockIdx.x;              // 512 blocks: b*NSEG + is
  int b  = blk >> 6;
  int is = blk & (NSEG - 1);
  int t = threadIdx.x;
  int ibase = is * SROWS;
  __shared__ float a1s[SROWS], e1s[SROWS], f1s[SROWS];
  if (t < SROWS) {
    int gi = b * N_ + ibase + t;
    a1s[t] = a1[gi]; e1s[t] = e1[gi]; f1s[t] = f1[gi];
  }
  __syncthreads();
  int j0 = t * 8;
  float4 a2lo = *(const float4*)(a2 + b * N_ + j0);
  float4 a2hi = *(const float4*)(a2 + b * N_ + j0 + 4);
  float a2v[8] = {a2lo.x, a2lo.y, a2lo.z, a2lo.w, a2hi.x, a2hi.y, a2hi.z, a2hi.w};
  float SA[8], SB[8];
  #pragma unroll
  for (int e = 0; e < 8; ++e) { SA[e] = 0.f; SB[e] = 0.f; }
  const int* arow = adj + ((size_t)(b * N_ + ibase)) * N_ + j0;
  unsigned char* mrow = maskB + (size_t)(b * N_ + ibase) * (N_ / 8) + t;
  #pragma unroll 4
  for (int ii = 0; ii < SROWS; ++ii) {
    int4 v0 = *(const int4*)(arow + (size_t)ii * N_);
    int4 v1 = *(const int4*)(arow + (size_t)ii * N_ + 4);
    float a1i = a1s[ii], e1i = e1s[ii], f1i = f1s[ii];
    int vals[8] = {v0.x, v0.y, v0.z, v0.w, v1.x, v1.y, v1.z, v1.w};
    unsigned int mb = 0;
    #pragma unroll
    for (int e = 0; e < 8; ++e) {
      bool pred = vals[e] != 0;
      mb |= pred ? (1u << e) : 0u;
      float tt = a1i + a2v[e];
      bool gt = tt > 0.f;
      SA[e] += (pred && gt)  ? e1i : 0.f;
      SB[e] += (pred && !gt) ? f1i : 0.f;
    }
    mrow[(size_t)ii * (N_ / 8)] = (unsigned char)mb;
  }
  float* pA = partA + ((size_t)(b * NSEG + is)) * N_ + j0;
  float* pB = partB + ((size_t)(b * NSEG + is)) * N_ + j0;
  *(float4*)(pA)     = float4{SA[0], SA[1], SA[2], SA[3]};
  *(float4*)(pA + 4) = float4{SA[4], SA[5], SA[6], SA[7]};
  *(float4*)(pB)     = float4{SB[0], SB[1], SB[2], SB[3]};
  *(float4*)(pB + 4) = float4{SB[4], SB[5], SB[6], SB[7]};
}

// ---- kernel 3: finish column stats -> E2/s, F2/s ----
__global__ __launch_bounds__(256) void k_colfin(
    const float* __restrict__ partA, const float* __restrict__ partB,
    const float* __restrict__ e2, const float* __restrict__ f2,
    float* __restrict__ e2rs, float* __restrict__ f2rs) {
  int g = blockIdx.x * 256 + threadIdx.x;   // 16384
  int b = g >> 11, j = g & (N_ - 1);
  float SA = 0.f, SB = 0.f;
  #pragma unroll 8
  for (int is = 0; is < NSEG; ++is) {
    SA += partA[((size_t)(b * NSEG + is)) * N_ + j];
    SB += partB[((size_t)(b * NSEG + is)) * N_ + j];
  }
  float s = e2[g] * SA + f2[g] * SB;
  float rs = s > 0.f ? 1.f / s : 0.f;
  e2rs[g] = e2[g] * rs;
  f2rs[g] = f2[g] * rs;
}

// ---- kernel 4: barrier-free fused att@h + elu + (hid @ han_w + b) ----
// grid 256 (1 block/CU), 512 threads = 8 waves: si = w&3 (i-slice of 16 rows),
// dh = w>>2 (d-half of 128). Each wave builds its OWN A-fragments (att) for
// its 16 rows -> no cross-wave sharing -> ZERO barriers in the K loop; the 4
// si-waves of a d-half read identical hT addresses (L1 dedupe). att sources
// + swizzled mask preloaded to LDS once. d-tile=256 keeps GEMM2 fused.
__global__ __launch_bounds__(512) void k_attmm(
    const bf16* __restrict__ hT, const unsigned char* __restrict__ maskB,
    const float* __restrict__ a1, const float* __restrict__ e1, const float* __restrict__ f1,
    const float* __restrict__ a2, const float* __restrict__ e2rs, const float* __restrict__ f2rs,
    const bf16* __restrict__ hwt, const float* __restrict__ hb,
    float* __restrict__ out) {
  __shared__ float s_src[3 * N_];             // a2 | e2rs | f2rs (24 KB)
  __shared__ unsigned char s_mask[64 * 256];  // mask rows, 8B-block XOR-swizzled (16 KB)
  __shared__ char s_hid[64 * 512];            // hid tile, 16B-chunk XOR-swizzled (32 KB)

  int blk = blockIdx.x;                 // 256 blocks
  int b  = blk & 7;                     // XCD pin: batch b's hT stays in XCD b's L2
  int i0 = (blk >> 3) * 64;
  int t = threadIdx.x, w = t >> 6, l = t & 63;
  int l15 = l & 15, lg = l >> 4;
  int si = w & 3, dh = w >> 2;

  // ---- preload att sources (1536 float4) ----
  #pragma unroll
  for (int s = 0; s < 3; ++s) {
    int idx = t + s * 512;
    int arr = idx >> 9, pos = (idx & 511) * 4;
    const float* src = (arr == 0) ? (a2 + b * N_) : (arr == 1) ? (e2rs + b * N_) : (f2rs + b * N_);
    *(float4*)(s_src + arr * N_ + pos) = *(const float4*)(src + pos);
  }
  // ---- preload mask rows i0..i0+63, XOR-swizzled in 8-byte blocks ----
  {
    int row = t >> 3, seg = t & 7;      // 32 B per thread
    const unsigned long long* g = (const unsigned long long*)
        (maskB + ((size_t)(b * N_ + i0 + row)) * (N_ / 8) + seg * 32);
    int sw = (row & 31) << 3;
    #pragma unroll
    for (int k2 = 0; k2 < 4; ++k2) {
      int cb = seg * 32 + k2 * 8;
      *(unsigned long long*)(s_mask + row * 256 + (cb ^ sw)) = g[k2];
    }
  }
  __syncthreads();

  int irow = si * 16 + l15;             // this lane's A-fragment row (block-local)
  int gi = b * N_ + i0 + irow;
  float a1i = a1[gi], e1i = e1[gi], f1i = f1[gi];
  const bf16* hTb = hT + (size_t)b * D_ * N_;
  const bf16* hrow0 = hTb + (size_t)(dh * 128 + l15) * N_;
  int mswz = (irow & 31) << 3;
  const unsigned char* mline = s_mask + irow * 256;

  f32x4 acc[8];
  #pragma unroll
  for (int ds = 0; ds < 8; ++ds) acc[ds] = f32x4{0.f, 0.f, 0.f, 0.f};

  // ---- barrier-free K loop: 64 steps of k=32 ----
  #pragma unroll 4
  for (int ks = 0; ks < 64; ++ks) {
    int jb = ks * 32 + lg * 8;
    float4 p0 = *(const float4*)(s_src + jb);
    float4 p1 = *(const float4*)(s_src + jb + 4);
    float4 q0 = *(const float4*)(s_src + N_ + jb);
    float4 q1 = *(const float4*)(s_src + N_ + jb + 4);
    float4 r0 = *(const float4*)(s_src + 2 * N_ + jb);
    float4 r1 = *(const float4*)(s_src + 2 * N_ + jb + 4);
    unsigned int m = mline[(ks * 4 + lg) ^ mswz];
    float a2v[8] = {p0.x,p0.y,p0.z,p0.w,p1.x,p1.y,p1.z,p1.w};
    float ev[8]  = {q0.x,q0.y,q0.z,q0.w,q1.x,q1.y,q1.z,q1.w};
    float fv[8]  = {r0.x,r0.y,r0.z,r0.w,r1.x,r1.y,r1.z,r1.w};
    bf16x8 av;
    #pragma unroll
    for (int e = 0; e < 8; ++e) {
      float tt = a1i + a2v[e];
      bool sel = tt > 0.f;
      float vv = (sel ? e1i : f1i) * (sel ? ev[e] : fv[e]);
      vv = ((m >> e) & 1u) ? vv : 0.f;
      av[e] = (bf16)vv;
    }
    #pragma unroll
    for (int ds = 0; ds < 8; ++ds) {
      bf16x8 bfr = *(const bf16x8*)(hrow0 + (size_t)ds * 16 * N_ + jb);
      acc[ds] = __builtin_amdgcn_mfma_f32_16x16x32_bf16(av, bfr, acc[ds], 0, 0, 0);
    }
  }

  // ---- elu -> bf16 hid tile into swizzled LDS ----
  #pragma unroll
  for (int ds = 0; ds < 8; ++ds) {
    int d = dh * 128 + ds * 16 + l15;
    int c = d >> 3, dby = (d & 7) * 2;
    #pragma unroll
    for (int r = 0; r < 4; ++r) {
      int il = si * 16 + lg * 4 + r;
      float vv = acc[ds][r];
      float hv = vv > 0.f ? vv : __expf(vv) - 1.f;
      *(bf16*)(s_hid + il * 512 + ((c ^ (il & 31)) * 16) + dby) = (bf16)hv;
    }
  }
  __syncthreads();

  // ---- out = hid @ han_w + han_b ----
  f32x4 acc2[8];
  #pragma unroll
  for (int ds = 0; ds < 8; ++ds) acc2[ds] = f32x4{0.f, 0.f, 0.f, 0.f};
  #pragma unroll
  for (int kh = 0; kh < 8; ++kh) {
    int kc = kh * 4 + lg;
    int ra = si * 16 + l15;
    bf16x8 afr = *(const bf16x8*)(s_hid + ra * 512 + ((kc ^ (ra & 31)) * 16));
    #pragma unroll
    for (int ds = 0; ds < 8; ++ds) {
      bf16x8 bfr = *(const bf16x8*)(
          hwt + (size_t)(dh * 128 + ds * 16 + l15) * D_ + kh * 32 + lg * 8);
      acc2[ds] = __builtin_amdgcn_mfma_f32_16x16x32_bf16(afr, bfr, acc2[ds], 0, 0, 0);
    }
  }
  #pragma unroll
  for (int ds = 0; ds < 8; ++ds) {
    int d = dh * 128 + ds * 16 + l15;
    float bias = hb[d];
    #pragma unroll
    for (int r = 0; r < 4; ++r) {
      int i = i0 + si * 16 + lg * 4 + r;
      out[((size_t)(b * N_ + i)) * D_ + d] = acc2[ds][r] + bias;
    }
  }
}

extern "C" void kernel_launch(void* const* d_in, const int* in_sizes, int n_in,
                              void* d_out, int out_size, void* d_ws, size_t ws_size,
                              hipStream_t stream) {
  (void)in_sizes; (void)n_in; (void)out_size; (void)ws_size;
  const float* x   = (const float*)d_in[0];
  const int*   adj = (const int*)d_in[1];
  const float* W   = (const float*)d_in[2];
  const float* a   = (const float*)d_in[3];
  const float* hw  = (const float*)d_in[4];
  const float* hb  = (const float*)d_in[5];
  float* out = (float*)d_out;

  char* ws = (char*)d_ws;
  size_t off = 0;
  auto alloc = [&](size_t bytes) -> char* {
    char* p = ws + off;
    off += (bytes + 255) & ~(size_t)255;
    return p;
  };
  float* a1   = (float*)alloc(BN * 4);
  float* e1   = (float*)alloc(BN * 4);
  float* f1   = (float*)alloc(BN * 4);
  float* a2   = (float*)alloc(BN * 4);
  float* e2   = (float*)alloc(BN * 4);
  float* f2   = (float*)alloc(BN * 4);
  float* e2rs = (float*)alloc(BN * 4);
  float* f2rs = (float*)alloc(BN * 4);
  float* partA = (float*)alloc((size_t)B_ * NSEG * N_ * 4);   // 4 MB
  float* partB = (float*)alloc((size_t)B_ * NSEG * N_ * 4);   // 4 MB
  unsigned char* maskB = (unsigned char*)alloc((size_t)BN * (N_ / 8)); // 4 MB
  bf16* hT  = (bf16*)alloc((size_t)B_ * D_ * N_ * 2);   // 8 MB
  bf16* wt  = (bf16*)alloc((size_t)D_ * D_ * 2);
  bf16* hwt = (bf16*)alloc((size_t)D_ * D_ * 2);

  k_transpose_w<<<256, 256, 0, stream>>>(W, hw, wt, hwt);
  k_gemm_h<<<256, 256, 0, stream>>>(x, wt, a, hT, a1, e1, f1, a2, e2, f2);
  k_colstats<<<B_ * NSEG, 256, 0, stream>>>(adj, a1, e1, f1, a2, partA, partB, maskB);
  k_colfin<<<BN / 256, 256, 0, stream>>>(partA, partB, e2, f2, e2rs, f2rs);
  k_attmm<<<256, 512, 0, stream>>>(hT, maskB, a1, e1, f1, a2, e2rs, f2rs,
                                   hwt, hb, out);
}

// Round 6
// 194.447 us; speedup vs baseline: 1.1530x; 1.1530x over previous
//
#include <hip/hip_runtime.h>
#include <hip/hip_bf16.h>
#include <stdint.h>

#define B_ 8
#define N_ 2048
#define D_ 256
#define BN (B_*N_)
#define NSEG 64
#define SROWS (N_/NSEG)   // 32 rows per segment

typedef __bf16 bf16;
typedef bf16 bf16x8 __attribute__((ext_vector_type(8)));
typedef bf16 bf16x4 __attribute__((ext_vector_type(4)));
typedef float f32x4 __attribute__((ext_vector_type(4)));

// ---- kernel 0: transpose weights to bf16 [d][k] ----
__global__ __launch_bounds__(256) void k_transpose_w(
    const float* __restrict__ w, const float* __restrict__ hw,
    bf16* __restrict__ wt, bf16* __restrict__ hwt) {
  int t = blockIdx.x * 256 + threadIdx.x;   // 65536 total
  int d = t >> 8, k = t & 255;
  wt[t]  = (bf16)w[k * D_ + d];
  hwt[t] = (bf16)hw[k * D_ + d];
}

// ---- kernel 1: h^T = (x@W)^T in bf16 (MFMA), fused with a1/a2 row stats ----
__global__ __launch_bounds__(256) void k_gemm_h(
    const float* __restrict__ x, const bf16* __restrict__ wt,
    const float* __restrict__ avec, bf16* __restrict__ hT,
    float* __restrict__ a1, float* __restrict__ e1, float* __restrict__ f1,
    float* __restrict__ a2, float* __restrict__ e2, float* __restrict__ f2) {
  int blk = blockIdx.x;            // 256 blocks
  int b = blk >> 5;
  int j0 = (blk & 31) * 64;
  int w = threadIdx.x >> 6, l = threadIdx.x & 63;
  int jr = j0 + w * 16 + (l & 15);
  const float* xrow = x + ((size_t)(b * N_ + jr)) * D_;
  int koff = 8 * (l >> 4);
  f32x4 acc[16];
  #pragma unroll
  for (int i = 0; i < 16; ++i) acc[i] = f32x4{0.f, 0.f, 0.f, 0.f};
  float s1 = 0.f, s2 = 0.f;
  for (int kb = 0; kb < D_; kb += 32) {
    float4 xa = *(const float4*)(xrow + kb + koff);
    float4 xb = *(const float4*)(xrow + kb + koff + 4);
    float4 ua = *(const float4*)(avec + kb + koff);
    float4 ub = *(const float4*)(avec + kb + koff + 4);
    float4 va = *(const float4*)(avec + D_ + kb + koff);
    float4 vb = *(const float4*)(avec + D_ + kb + koff + 4);
    s1 = fmaf(xa.x, ua.x, fmaf(xa.y, ua.y, fmaf(xa.z, ua.z, fmaf(xa.w, ua.w, s1))));
    s1 = fmaf(xb.x, ub.x, fmaf(xb.y, ub.y, fmaf(xb.z, ub.z, fmaf(xb.w, ub.w, s1))));
    s2 = fmaf(xa.x, va.x, fmaf(xa.y, va.y, fmaf(xa.z, va.z, fmaf(xa.w, va.w, s2))));
    s2 = fmaf(xb.x, vb.x, fmaf(xb.y, vb.y, fmaf(xb.z, vb.z, fmaf(xb.w, vb.w, s2))));
    bf16x8 af = { (bf16)xa.x, (bf16)xa.y, (bf16)xa.z, (bf16)xa.w,
                  (bf16)xb.x, (bf16)xb.y, (bf16)xb.z, (bf16)xb.w };
    #pragma unroll
    for (int dt = 0; dt < 16; ++dt) {
      bf16x8 bfr = *(const bf16x8*)(wt + (dt * 16 + (l & 15)) * D_ + kb + koff);
      acc[dt] = __builtin_amdgcn_mfma_f32_16x16x32_bf16(af, bfr, acc[dt], 0, 0, 0);
    }
  }
  // row-stat reduction: lanes l, l^16, l^32, l^48 share row jr
  s1 += __shfl_xor(s1, 16); s1 += __shfl_xor(s1, 32);
  s2 += __shfl_xor(s2, 16); s2 += __shfl_xor(s2, 32);
  if (l < 16) {
    int row = b * N_ + j0 + w * 16 + l;
    a1[row] = s1; e1[row] = __expf(s1); f1[row] = __expf(0.2f * s1);
    a2[row] = s2; e2[row] = __expf(s2); f2[row] = __expf(0.2f * s2);
  }
  int jw = j0 + w * 16 + (l >> 4) * 4;
  #pragma unroll
  for (int dt = 0; dt < 16; ++dt) {
    int d = dt * 16 + (l & 15);
    bf16x4 o = { (bf16)acc[dt][0], (bf16)acc[dt][1], (bf16)acc[dt][2], (bf16)acc[dt][3] };
    *(bf16x4*)(hT + ((size_t)(b * D_ + d)) * N_ + jw) = o;   // hT[b][d][j]
  }
}

// ---- kernel 2: column partial sums + adj->bitmask (vectorized, ballot-free) ----
__global__ __launch_bounds__(256) void k_colstats(
    const int* __restrict__ adj,
    const float* __restrict__ a1, const float* __restrict__ e1, const float* __restrict__ f1,
    const float* __restrict__ a2,
    float* __restrict__ partA, float* __restrict__ partB,
    unsigned char* __restrict__ maskB) {
  int blk = blockIdx.x;              // 512 blocks: b*NSEG + is
  int b  = blk >> 6;
  int is = blk & (NSEG - 1);
  int t = threadIdx.x;
  int ibase = is * SROWS;
  __shared__ float a1s[SROWS], e1s[SROWS], f1s[SROWS];
  if (t < SROWS) {
    int gi = b * N_ + ibase + t;
    a1s[t] = a1[gi]; e1s[t] = e1[gi]; f1s[t] = f1[gi];
  }
  __syncthreads();
  int j0 = t * 8;
  float4 a2lo = *(const float4*)(a2 + b * N_ + j0);
  float4 a2hi = *(const float4*)(a2 + b * N_ + j0 + 4);
  float a2v[8] = {a2lo.x, a2lo.y, a2lo.z, a2lo.w, a2hi.x, a2hi.y, a2hi.z, a2hi.w};
  float SA[8], SB[8];
  #pragma unroll
  for (int e = 0; e < 8; ++e) { SA[e] = 0.f; SB[e] = 0.f; }
  const int* arow = adj + ((size_t)(b * N_ + ibase)) * N_ + j0;
  unsigned char* mrow = maskB + (size_t)(b * N_ + ibase) * (N_ / 8) + t;
  #pragma unroll 4
  for (int ii = 0; ii < SROWS; ++ii) {
    int4 v0 = *(const int4*)(arow + (size_t)ii * N_);
    int4 v1 = *(const int4*)(arow + (size_t)ii * N_ + 4);
    float a1i = a1s[ii], e1i = e1s[ii], f1i = f1s[ii];
    int vals[8] = {v0.x, v0.y, v0.z, v0.w, v1.x, v1.y, v1.z, v1.w};
    unsigned int mb = 0;
    #pragma unroll
    for (int e = 0; e < 8; ++e) {
      bool pred = vals[e] != 0;
      mb |= pred ? (1u << e) : 0u;
      float tt = a1i + a2v[e];
      bool gt = tt > 0.f;
      SA[e] += (pred && gt)  ? e1i : 0.f;
      SB[e] += (pred && !gt) ? f1i : 0.f;
    }
    mrow[(size_t)ii * (N_ / 8)] = (unsigned char)mb;
  }
  float* pA = partA + ((size_t)(b * NSEG + is)) * N_ + j0;
  float* pB = partB + ((size_t)(b * NSEG + is)) * N_ + j0;
  *(float4*)(pA)     = float4{SA[0], SA[1], SA[2], SA[3]};
  *(float4*)(pA + 4) = float4{SA[4], SA[5], SA[6], SA[7]};
  *(float4*)(pB)     = float4{SB[0], SB[1], SB[2], SB[3]};
  *(float4*)(pB + 4) = float4{SB[4], SB[5], SB[6], SB[7]};
}

// ---- kernel 3: finish column stats -> E2/s, F2/s ----
__global__ __launch_bounds__(256) void k_colfin(
    const float* __restrict__ partA, const float* __restrict__ partB,
    const float* __restrict__ e2, const float* __restrict__ f2,
    float* __restrict__ e2rs, float* __restrict__ f2rs) {
  int g = blockIdx.x * 256 + threadIdx.x;   // 16384
  int b = g >> 11, j = g & (N_ - 1);
  float SA = 0.f, SB = 0.f;
  #pragma unroll 8
  for (int is = 0; is < NSEG; ++is) {
    SA += partA[((size_t)(b * NSEG + is)) * N_ + j];
    SB += partB[((size_t)(b * NSEG + is)) * N_ + j];
  }
  float s = e2[g] * SA + f2[g] * SB;
  float rs = s > 0.f ? 1.f / s : 0.f;
  e2rs[g] = e2[g] * rs;
  f2rs[g] = f2[g] * rs;
}

// ---- kernel 4: barrier-free fused att@h + elu + (hid @ han_w + b) ----
// grid 256 (1 block/CU), 512 threads = 8 waves: si = w&3 (i-slice of 16 rows),
// dh = w>>2 (d-half of 128). Each wave builds its OWN A-fragments; ZERO
// barriers in the K loop. B-frags are explicitly double-buffered in registers
// (unroll-2, one K-step ahead) so 8 loads stay in flight under each MFMA
// cluster -- R5's regression was the absence of exactly this pipeline.
__global__ __launch_bounds__(512) void k_attmm(
    const bf16* __restrict__ hT, const unsigned char* __restrict__ maskB,
    const float* __restrict__ a1, const float* __restrict__ e1, const float* __restrict__ f1,
    const float* __restrict__ a2, const float* __restrict__ e2rs, const float* __restrict__ f2rs,
    const bf16* __restrict__ hwt, const float* __restrict__ hb,
    float* __restrict__ out) {
  __shared__ float s_src[3 * N_];             // a2 | e2rs | f2rs (24 KB)
  __shared__ unsigned char s_mask[64 * 256];  // mask rows, 8B-block XOR-swizzled (16 KB)
  __shared__ char s_hid[64 * 512];            // hid tile, 16B-chunk XOR-swizzled (32 KB)

  int blk = blockIdx.x;                 // 256 blocks
  int b  = blk & 7;                     // XCD pin: batch b's hT stays in XCD b's L2
  int i0 = (blk >> 3) * 64;
  int t = threadIdx.x, w = t >> 6, l = t & 63;
  int l15 = l & 15, lg = l >> 4;
  int si = w & 3, dh = w >> 2;

  // ---- preload att sources (1536 float4) ----
  #pragma unroll
  for (int s = 0; s < 3; ++s) {
    int idx = t + s * 512;
    int arr = idx >> 9, pos = (idx & 511) * 4;
    const float* src = (arr == 0) ? (a2 + b * N_) : (arr == 1) ? (e2rs + b * N_) : (f2rs + b * N_);
    *(float4*)(s_src + arr * N_ + pos) = *(const float4*)(src + pos);
  }
  // ---- preload mask rows i0..i0+63, XOR-swizzled in 8-byte blocks ----
  {
    int row = t >> 3, seg = t & 7;      // 32 B per thread
    const unsigned long long* g = (const unsigned long long*)
        (maskB + ((size_t)(b * N_ + i0 + row)) * (N_ / 8) + seg * 32);
    int sw = (row & 31) << 3;
    #pragma unroll
    for (int k2 = 0; k2 < 4; ++k2) {
      int cb = seg * 32 + k2 * 8;
      *(unsigned long long*)(s_mask + row * 256 + (cb ^ sw)) = g[k2];
    }
  }
  __syncthreads();

  int irow = si * 16 + l15;             // this lane's A-fragment row (block-local)
  int gi = b * N_ + i0 + irow;
  float a1i = a1[gi], e1i = e1[gi], f1i = f1[gi];
  const bf16* hTb = hT + (size_t)b * D_ * N_;
  const bf16* hrow0 = hTb + (size_t)(dh * 128 + l15) * N_;
  int mswz = (irow & 31) << 3;
  const unsigned char* mline = s_mask + irow * 256;

  // att A-fragment builder for K-step ks (k = ks*32 .. +32, this lane: lg*8..+8)
  auto build_av = [&](int ks) -> bf16x8 {
    int jb = ks * 32 + lg * 8;
    float4 p0 = *(const float4*)(s_src + jb);
    float4 p1 = *(const float4*)(s_src + jb + 4);
    float4 q0 = *(const float4*)(s_src + N_ + jb);
    float4 q1 = *(const float4*)(s_src + N_ + jb + 4);
    float4 r0 = *(const float4*)(s_src + 2 * N_ + jb);
    float4 r1 = *(const float4*)(s_src + 2 * N_ + jb + 4);
    unsigned int m = mline[(ks * 4 + lg) ^ mswz];
    float a2v[8] = {p0.x,p0.y,p0.z,p0.w,p1.x,p1.y,p1.z,p1.w};
    float ev[8]  = {q0.x,q0.y,q0.z,q0.w,q1.x,q1.y,q1.z,q1.w};
    float fv[8]  = {r0.x,r0.y,r0.z,r0.w,r1.x,r1.y,r1.z,r1.w};
    bf16x8 av;
    #pragma unroll
    for (int e = 0; e < 8; ++e) {
      float tt = a1i + a2v[e];
      bool sel = tt > 0.f;
      float vv = (sel ? e1i : f1i) * (sel ? ev[e] : fv[e]);
      vv = ((m >> e) & 1u) ? vv : 0.f;
      av[e] = (bf16)vv;
    }
    return av;
  };

  f32x4 acc[8];
  #pragma unroll
  for (int ds = 0; ds < 8; ++ds) acc[ds] = f32x4{0.f, 0.f, 0.f, 0.f};

  // ---- K loop: 64 steps of k=32, unroll-2 with register double-buffer ----
  bf16x8 bA[8], bB[8];
  #pragma unroll
  for (int ds = 0; ds < 8; ++ds)
    bA[ds] = *(const bf16x8*)(hrow0 + (size_t)ds * 16 * N_ + lg * 8);   // ks=0

  for (int ks = 0; ks < 64; ks += 2) {
    // issue loads for ks+1 (fly under build+MFMA of ks)
    int jb1 = (ks + 1) * 32 + lg * 8;
    #pragma unroll
    for (int ds = 0; ds < 8; ++ds)
      bB[ds] = *(const bf16x8*)(hrow0 + (size_t)ds * 16 * N_ + jb1);
    bf16x8 avA = build_av(ks);
    #pragma unroll
    for (int ds = 0; ds < 8; ++ds)
      acc[ds] = __builtin_amdgcn_mfma_f32_16x16x32_bf16(avA, bA[ds], acc[ds], 0, 0, 0);
    // issue loads for ks+2 (wrap at end; extra read stays in-bounds workspace)
    int jb2 = ((ks + 2) & 63) * 32 + lg * 8;
    #pragma unroll
    for (int ds = 0; ds < 8; ++ds)
      bA[ds] = *(const bf16x8*)(hrow0 + (size_t)ds * 16 * N_ + jb2);
    bf16x8 avB = build_av(ks + 1);
    #pragma unroll
    for (int ds = 0; ds < 8; ++ds)
      acc[ds] = __builtin_amdgcn_mfma_f32_16x16x32_bf16(avB, bB[ds], acc[ds], 0, 0, 0);
  }

  // ---- elu -> bf16 hid tile into swizzled LDS ----
  #pragma unroll
  for (int ds = 0; ds < 8; ++ds) {
    int d = dh * 128 + ds * 16 + l15;
    int c = d >> 3, dby = (d & 7) * 2;
    #pragma unroll
    for (int r = 0; r < 4; ++r) {
      int il = si * 16 + lg * 4 + r;
      float vv = acc[ds][r];
      float hv = vv > 0.f ? vv : __expf(vv) - 1.f;
      *(bf16*)(s_hid + il * 512 + ((c ^ (il & 31)) * 16) + dby) = (bf16)hv;
    }
  }
  __syncthreads();

  // ---- out = hid @ han_w + han_b ----
  f32x4 acc2[8];
  #pragma unroll
  for (int ds = 0; ds < 8; ++ds) acc2[ds] = f32x4{0.f, 0.f, 0.f, 0.f};
  #pragma unroll
  for (int kh = 0; kh < 8; ++kh) {
    int kc = kh * 4 + lg;
    int ra = si * 16 + l15;
    bf16x8 afr = *(const bf16x8*)(s_hid + ra * 512 + ((kc ^ (ra & 31)) * 16));
    #pragma unroll
    for (int ds = 0; ds < 8; ++ds) {
      bf16x8 bfr = *(const bf16x8*)(
          hwt + (size_t)(dh * 128 + ds * 16 + l15) * D_ + kh * 32 + lg * 8);
      acc2[ds] = __builtin_amdgcn_mfma_f32_16x16x32_bf16(afr, bfr, acc2[ds], 0, 0, 0);
    }
  }
  #pragma unroll
  for (int ds = 0; ds < 8; ++ds) {
    int d = dh * 128 + ds * 16 + l15;
    float bias = hb[d];
    #pragma unroll
    for (int r = 0; r < 4; ++r) {
      int i = i0 + si * 16 + lg * 4 + r;
      out[((size_t)(b * N_ + i)) * D_ + d] = acc2[ds][r] + bias;
    }
  }
}

extern "C" void kernel_launch(void* const* d_in, const int* in_sizes, int n_in,
                              void* d_out, int out_size, void* d_ws, size_t ws_size,
                              hipStream_t stream) {
  (void)in_sizes; (void)n_in; (void)out_size; (void)ws_size;
  const float* x   = (const float*)d_in[0];
  const int*   adj = (const int*)d_in[1];
  const float* W   = (const float*)d_in[2];
  const float* a   = (const float*)d_in[3];
  const float* hw  = (const float*)d_in[4];
  const float* hb  = (const float*)d_in[5];
  float* out = (float*)d_out;

  char* ws = (char*)d_ws;
  size_t off = 0;
  auto alloc = [&](size_t bytes) -> char* {
    char* p = ws + off;
    off += (bytes + 255) & ~(size_t)255;
    return p;
  };
  float* a1   = (float*)alloc(BN * 4);
  float* e1   = (float*)alloc(BN * 4);
  float* f1   = (float*)alloc(BN * 4);
  float* a2   = (float*)alloc(BN * 4);
  float* e2   = (float*)alloc(BN * 4);
  float* f2   = (float*)alloc(BN * 4);
  float* e2rs = (float*)alloc(BN * 4);
  float* f2rs = (float*)alloc(BN * 4);
  float* partA = (float*)alloc((size_t)B_ * NSEG * N_ * 4);   // 4 MB
  float* partB = (float*)alloc((size_t)B_ * NSEG * N_ * 4);   // 4 MB
  unsigned char* maskB = (unsigned char*)alloc((size_t)BN * (N_ / 8)); // 4 MB
  bf16* hT  = (bf16*)alloc((size_t)B_ * D_ * N_ * 2);   // 8 MB
  bf16* wt  = (bf16*)alloc((size_t)D_ * D_ * 2);
  bf16* hwt = (bf16*)alloc((size_t)D_ * D_ * 2);

  k_transpose_w<<<256, 256, 0, stream>>>(W, hw, wt, hwt);
  k_gemm_h<<<256, 256, 0, stream>>>(x, wt, a, hT, a1, e1, f1, a2, e2, f2);
  k_colstats<<<B_ * NSEG, 256, 0, stream>>>(adj, a1, e1, f1, a2, partA, partB, maskB);
  k_colfin<<<BN / 256, 256, 0, stream>>>(partA, partB, e2, f2, e2rs, f2rs);
  k_attmm<<<256, 512, 0, stream>>>(hT, maskB, a1, e1, f1, a2, e2rs, f2rs,
                                   hwt, hb, out);
}

// Round 7
// 111.257 us; speedup vs baseline: 2.0151x; 1.7477x over previous
//
#include <hip/hip_runtime.h>
#include <hip/hip_bf16.h>
#include <stdint.h>

#define B_ 8
#define N_ 2048
#define D_ 256
#define BN (B_*N_)
#define NSEG 64
#define SROWS (N_/NSEG)   // 32 rows per segment

typedef __bf16 bf16;
typedef bf16 bf16x8 __attribute__((ext_vector_type(8)));
typedef bf16 bf16x4 __attribute__((ext_vector_type(4)));
typedef float f32x4 __attribute__((ext_vector_type(4)));

// async global->LDS, 16 B per lane; LDS dest must be wave-uniform base + lane*16
__device__ __forceinline__ void gload16(const void* g, void* l) {
  __builtin_amdgcn_global_load_lds(
      (const __attribute__((address_space(1))) unsigned int*)g,
      (__attribute__((address_space(3))) unsigned int*)l,
      16, 0, 0);
}

// ---- kernel 0: transpose weights to bf16 [d][k] ----
__global__ __launch_bounds__(256) void k_transpose_w(
    const float* __restrict__ w, const float* __restrict__ hw,
    bf16* __restrict__ wt, bf16* __restrict__ hwt) {
  int t = blockIdx.x * 256 + threadIdx.x;   // 65536 total
  int d = t >> 8, k = t & 255;
  wt[t]  = (bf16)w[k * D_ + d];
  hwt[t] = (bf16)hw[k * D_ + d];
}

// ---- kernel 1: h^T = (x@W)^T in bf16 (MFMA), fused with a1/a2 row stats ----
__global__ __launch_bounds__(256) void k_gemm_h(
    const float* __restrict__ x, const bf16* __restrict__ wt,
    const float* __restrict__ avec, bf16* __restrict__ hT,
    float* __restrict__ a1, float* __restrict__ e1, float* __restrict__ f1,
    float* __restrict__ a2, float* __restrict__ e2, float* __restrict__ f2) {
  int blk = blockIdx.x;            // 256 blocks
  int b = blk >> 5;
  int j0 = (blk & 31) * 64;
  int w = threadIdx.x >> 6, l = threadIdx.x & 63;
  int jr = j0 + w * 16 + (l & 15);
  const float* xrow = x + ((size_t)(b * N_ + jr)) * D_;
  int koff = 8 * (l >> 4);
  f32x4 acc[16];
  #pragma unroll
  for (int i = 0; i < 16; ++i) acc[i] = f32x4{0.f, 0.f, 0.f, 0.f};
  float s1 = 0.f, s2 = 0.f;
  for (int kb = 0; kb < D_; kb += 32) {
    float4 xa = *(const float4*)(xrow + kb + koff);
    float4 xb = *(const float4*)(xrow + kb + koff + 4);
    float4 ua = *(const float4*)(avec + kb + koff);
    float4 ub = *(const float4*)(avec + kb + koff + 4);
    float4 va = *(const float4*)(avec + D_ + kb + koff);
    float4 vb = *(const float4*)(avec + D_ + kb + koff + 4);
    s1 = fmaf(xa.x, ua.x, fmaf(xa.y, ua.y, fmaf(xa.z, ua.z, fmaf(xa.w, ua.w, s1))));
    s1 = fmaf(xb.x, ub.x, fmaf(xb.y, ub.y, fmaf(xb.z, ub.z, fmaf(xb.w, ub.w, s1))));
    s2 = fmaf(xa.x, va.x, fmaf(xa.y, va.y, fmaf(xa.z, va.z, fmaf(xa.w, va.w, s2))));
    s2 = fmaf(xb.x, vb.x, fmaf(xb.y, vb.y, fmaf(xb.z, vb.z, fmaf(xb.w, vb.w, s2))));
    bf16x8 af = { (bf16)xa.x, (bf16)xa.y, (bf16)xa.z, (bf16)xa.w,
                  (bf16)xb.x, (bf16)xb.y, (bf16)xb.z, (bf16)xb.w };
    #pragma unroll
    for (int dt = 0; dt < 16; ++dt) {
      bf16x8 bfr = *(const bf16x8*)(wt + (dt * 16 + (l & 15)) * D_ + kb + koff);
      acc[dt] = __builtin_amdgcn_mfma_f32_16x16x32_bf16(af, bfr, acc[dt], 0, 0, 0);
    }
  }
  s1 += __shfl_xor(s1, 16); s1 += __shfl_xor(s1, 32);
  s2 += __shfl_xor(s2, 16); s2 += __shfl_xor(s2, 32);
  if (l < 16) {
    int row = b * N_ + j0 + w * 16 + l;
    a1[row] = s1; e1[row] = __expf(s1); f1[row] = __expf(0.2f * s1);
    a2[row] = s2; e2[row] = __expf(s2); f2[row] = __expf(0.2f * s2);
  }
  int jw = j0 + w * 16 + (l >> 4) * 4;
  #pragma unroll
  for (int dt = 0; dt < 16; ++dt) {
    int d = dt * 16 + (l & 15);
    bf16x4 o = { (bf16)acc[dt][0], (bf16)acc[dt][1], (bf16)acc[dt][2], (bf16)acc[dt][3] };
    *(bf16x4*)(hT + ((size_t)(b * D_ + d)) * N_ + jw) = o;   // hT[b][d][j]
  }
}

// ---- kernel 2: column partial sums + adj->bitmask (vectorized, ballot-free) ----
__global__ __launch_bounds__(256) void k_colstats(
    const int* __restrict__ adj,
    const float* __restrict__ a1, const float* __restrict__ e1, const float* __restrict__ f1,
    const float* __restrict__ a2,
    float* __restrict__ partA, float* __restrict__ partB,
    unsigned char* __restrict__ maskB) {
  int blk = blockIdx.x;              // 512 blocks: b*NSEG + is
  int b  = blk >> 6;
  int is = blk & (NSEG - 1);
  int t = threadIdx.x;
  int ibase = is * SROWS;
  __shared__ float a1s[SROWS], e1s[SROWS], f1s[SROWS];
  if (t < SROWS) {
    int gi = b * N_ + ibase + t;
    a1s[t] = a1[gi]; e1s[t] = e1[gi]; f1s[t] = f1[gi];
  }
  __syncthreads();
  int j0 = t * 8;
  float4 a2lo = *(const float4*)(a2 + b * N_ + j0);
  float4 a2hi = *(const float4*)(a2 + b * N_ + j0 + 4);
  float a2v[8] = {a2lo.x, a2lo.y, a2lo.z, a2lo.w, a2hi.x, a2hi.y, a2hi.z, a2hi.w};
  float SA[8], SB[8];
  #pragma unroll
  for (int e = 0; e < 8; ++e) { SA[e] = 0.f; SB[e] = 0.f; }
  const int* arow = adj + ((size_t)(b * N_ + ibase)) * N_ + j0;
  unsigned char* mrow = maskB + (size_t)(b * N_ + ibase) * (N_ / 8) + t;
  #pragma unroll 4
  for (int ii = 0; ii < SROWS; ++ii) {
    int4 v0 = *(const int4*)(arow + (size_t)ii * N_);
    int4 v1 = *(const int4*)(arow + (size_t)ii * N_ + 4);
    float a1i = a1s[ii], e1i = e1s[ii], f1i = f1s[ii];
    int vals[8] = {v0.x, v0.y, v0.z, v0.w, v1.x, v1.y, v1.z, v1.w};
    unsigned int mb = 0;
    #pragma unroll
    for (int e = 0; e < 8; ++e) {
      bool pred = vals[e] != 0;
      mb |= pred ? (1u << e) : 0u;
      float tt = a1i + a2v[e];
      bool gt = tt > 0.f;
      SA[e] += (pred && gt)  ? e1i : 0.f;
      SB[e] += (pred && !gt) ? f1i : 0.f;
    }
    mrow[(size_t)ii * (N_ / 8)] = (unsigned char)mb;
  }
  float* pA = partA + ((size_t)(b * NSEG + is)) * N_ + j0;
  float* pB = partB + ((size_t)(b * NSEG + is)) * N_ + j0;
  *(float4*)(pA)     = float4{SA[0], SA[1], SA[2], SA[3]};
  *(float4*)(pA + 4) = float4{SA[4], SA[5], SA[6], SA[7]};
  *(float4*)(pB)     = float4{SB[0], SB[1], SB[2], SB[3]};
  *(float4*)(pB + 4) = float4{SB[4], SB[5], SB[6], SB[7]};
}

// ---- kernel 3: finish column stats -> E2/s, F2/s ----
__global__ __launch_bounds__(256) void k_colfin(
    const float* __restrict__ partA, const float* __restrict__ partB,
    const float* __restrict__ e2, const float* __restrict__ f2,
    float* __restrict__ e2rs, float* __restrict__ f2rs) {
  int g = blockIdx.x * 256 + threadIdx.x;   // 16384
  int b = g >> 11, j = g & (N_ - 1);
  float SA = 0.f, SB = 0.f;
  #pragma unroll 8
  for (int is = 0; is < NSEG; ++is) {
    SA += partA[((size_t)(b * NSEG + is)) * N_ + j];
    SB += partB[((size_t)(b * NSEG + is)) * N_ + j];
  }
  float s = e2[g] * SA + f2[g] * SB;
  float rs = s > 0.f ? 1.f / s : 0.f;
  e2rs[g] = e2[g] * rs;
  f2rs[g] = f2[g] * rs;
}

// ---- kernel 4: m97-style 2-phase staged att@h + elu + fused han_w GEMM ----
// grid 256 (1 block/CU, b=blk&7 XCD pin), 512 thr = 8 waves (iw=w&1, dw=w>>2? no: dw=w>>1).
// Tile 64i x 256d, BK=64 j-window, 32 steps. B staged via global_load_lds
// (pre-swizzled source, linear LDS dest); A (att) built once/step into dbuf LDS.
__global__ __launch_bounds__(512, 2) void k_attmm(
    const bf16* __restrict__ hT, const unsigned char* __restrict__ maskB,
    const float* __restrict__ a1v, const float* __restrict__ e1v, const float* __restrict__ f1v,
    const float* __restrict__ a2v, const float* __restrict__ e2rs, const float* __restrict__ f2rs,
    const bf16* __restrict__ hwt, const float* __restrict__ hb,
    float* __restrict__ out) {
  __shared__ __attribute__((aligned(128))) char smem[120 * 1024];
  char* s_b = smem;                                  // 2 x [256][64] bf16 (64 KB)
  char* s_a = smem + 65536;                          // 2 x [64][64] bf16 (16 KB)
  float* s_src = (float*)(smem + 81920);             // a2|e2rs|f2rs (24 KB)
  unsigned char* s_mask = (unsigned char*)(smem + 106496); // 64 rows x 256 B (16 KB)
  char* s_hid = smem;                                // alias of s_b buf0 after loop (32 KB)

  int blk = blockIdx.x;
  int b  = blk & 7;
  int i0 = (blk >> 3) * 64;
  int t = threadIdx.x, w = t >> 6, l = t & 63;
  int l15 = l & 15, lg = l >> 4;
  int iw = w & 1, dw = w >> 1;          // wave tile: 32i x 64d

  // ---- preload att sources ----
  #pragma unroll
  for (int s = 0; s < 3; ++s) {
    int idx = t + s * 512;
    int arr = idx >> 9, pos = (idx & 511) * 4;
    const float* src = (arr == 0) ? (a2v + b * N_) : (arr == 1) ? (e2rs + b * N_) : (f2rs + b * N_);
    *(float4*)(s_src + arr * N_ + pos) = *(const float4*)(src + pos);
  }
  // ---- preload mask rows i0..i0+63, XOR-swizzled in 8-byte blocks ----
  {
    int row = t >> 3, seg = t & 7;
    const unsigned long long* g = (const unsigned long long*)
        (maskB + ((size_t)(b * N_ + i0 + row)) * (N_ / 8) + seg * 32);
    int sw = (row & 31) << 3;
    #pragma unroll
    for (int k2 = 0; k2 < 4; ++k2) {
      int cb = seg * 32 + k2 * 8;
      *(unsigned long long*)(s_mask + row * 256 + (cb ^ sw)) = g[k2];
    }
  }

  int ib = t >> 3, jq = t & 7;          // A-build role: row ib, 8 cols
  int gi = b * N_ + i0 + ib;
  float a1i = a1v[gi], e1i = e1v[gi], f1i = f1v[gi];
  int mswz = (ib & 31) << 3;
  const unsigned char* mline = s_mask + ib * 256;
  const bf16* hTb = hT + (size_t)b * D_ * N_;

  f32x4 acc[2][4];
  #pragma unroll
  for (int is = 0; is < 2; ++is)
    #pragma unroll
    for (int ds = 0; ds < 4; ++ds) acc[is][ds] = f32x4{0.f, 0.f, 0.f, 0.f};

  __syncthreads();   // s_src / s_mask ready

  // ---- stage + build for window 0 ----
  #define STAGE_B(KB, NB) do {                                              \
    char* dstb = s_b + (NB) * 32768;                                        \
    _Pragma("unroll")                                                       \
    for (int r = 0; r < 4; ++r) {                                           \
      int c = r * 512 + t;                                                  \
      int dd = c >> 3, sub = c & 7;                                         \
      int ssub = sub ^ (dd & 7);                                            \
      gload16(hTb + (size_t)dd * N_ + (KB) + ssub * 8, dstb + c * 16);      \
    }                                                                       \
  } while (0)

  #define BUILD_A(KB, NB) do {                                              \
    int jb = (KB) + jq * 8;                                                 \
    float4 p0 = *(const float4*)(s_src + jb);                               \
    float4 p1 = *(const float4*)(s_src + jb + 4);                           \
    float4 q0 = *(const float4*)(s_src + N_ + jb);                          \
    float4 q1 = *(const float4*)(s_src + N_ + jb + 4);                      \
    float4 r0 = *(const float4*)(s_src + 2 * N_ + jb);                      \
    float4 r1 = *(const float4*)(s_src + 2 * N_ + jb + 4);                  \
    unsigned int m = mline[((((KB) >> 3) + jq)) ^ mswz];                    \
    float a2x[8] = {p0.x,p0.y,p0.z,p0.w,p1.x,p1.y,p1.z,p1.w};               \
    float evx[8] = {q0.x,q0.y,q0.z,q0.w,q1.x,q1.y,q1.z,q1.w};               \
    float fvx[8] = {r0.x,r0.y,r0.z,r0.w,r1.x,r1.y,r1.z,r1.w};               \
    bf16x8 av;                                                              \
    _Pragma("unroll")                                                       \
    for (int e = 0; e < 8; ++e) {                                           \
      float tt = a1i + a2x[e];                                              \
      bool sel = tt > 0.f;                                                  \
      float vv = (sel ? e1i : f1i) * (sel ? evx[e] : fvx[e]);               \
      vv = ((m >> e) & 1u) ? vv : 0.f;                                      \
      av[e] = (bf16)vv;                                                     \
    }                                                                       \
    *(bf16x8*)(s_a + (NB) * 8192 + ib * 128 + ((jq ^ (ib & 7)) * 16)) = av; \
  } while (0)

  STAGE_B(0, 0);
  BUILD_A(0, 0);
  __syncthreads();   // drains gloads (vmcnt) + A writes (lgkm)

  int cur = 0;
  for (int ks = 0; ks < 32; ++ks) {
    if (ks < 31) {
      int kbn = (ks + 1) * 64;
      STAGE_B(kbn, cur ^ 1);
      BUILD_A(kbn, cur ^ 1);
    }
    const char* sa = s_a + cur * 8192;
    const char* sb = s_b + cur * 32768;
    #pragma unroll
    for (int kh = 0; kh < 2; ++kh) {
      int kq = kh * 4 + lg;
      bf16x8 afr[2], bfr[4];
      #pragma unroll
      for (int is = 0; is < 2; ++is) {
        int ra = iw * 32 + is * 16 + l15;
        afr[is] = *(const bf16x8*)(sa + ra * 128 + ((kq ^ (ra & 7)) * 16));
      }
      #pragma unroll
      for (int ds = 0; ds < 4; ++ds) {
        int rb = dw * 64 + ds * 16 + l15;
        bfr[ds] = *(const bf16x8*)(sb + rb * 128 + ((kq ^ (rb & 7)) * 16));
      }
      #pragma unroll
      for (int is = 0; is < 2; ++is)
        #pragma unroll
        for (int ds = 0; ds < 4; ++ds)
          acc[is][ds] = __builtin_amdgcn_mfma_f32_16x16x32_bf16(
              afr[is], bfr[ds], acc[is][ds], 0, 0, 0);
    }
    __syncthreads();
    cur ^= 1;
  }

  // ---- elu -> bf16 hid tile into swizzled LDS (aliases s_b buf0) ----
  #pragma unroll
  for (int is = 0; is < 2; ++is) {
    #pragma unroll
    for (int ds = 0; ds < 4; ++ds) {
      int d = dw * 64 + ds * 16 + l15;
      int c = d >> 3, dby = (d & 7) * 2;
      #pragma unroll
      for (int r = 0; r < 4; ++r) {
        int il = iw * 32 + is * 16 + lg * 4 + r;
        float vv = acc[is][ds][r];
        float hv = vv > 0.f ? vv : __expf(vv) - 1.f;
        *(bf16*)(s_hid + il * 512 + ((c ^ (il & 31)) * 16) + dby) = (bf16)hv;
      }
    }
  }
  __syncthreads();

  // ---- out = hid @ han_w + han_b ----
  f32x4 acc2[2][4];
  #pragma unroll
  for (int is = 0; is < 2; ++is)
    #pragma unroll
    for (int ds = 0; ds < 4; ++ds) acc2[is][ds] = f32x4{0.f, 0.f, 0.f, 0.f};
  #pragma unroll
  for (int kh = 0; kh < 8; ++kh) {
    int kc = kh * 4 + lg;
    bf16x8 afr2[2];
    #pragma unroll
    for (int is = 0; is < 2; ++is) {
      int ra = iw * 32 + is * 16 + l15;
      afr2[is] = *(const bf16x8*)(s_hid + ra * 512 + ((kc ^ (ra & 31)) * 16));
    }
    #pragma unroll
    for (int ds = 0; ds < 4; ++ds) {
      int d2 = dw * 64 + ds * 16 + l15;
      bf16x8 bfr2 = *(const bf16x8*)(hwt + (size_t)d2 * D_ + kh * 32 + lg * 8);
      #pragma unroll
      for (int is = 0; is < 2; ++is)
        acc2[is][ds] = __builtin_amdgcn_mfma_f32_16x16x32_bf16(
            afr2[is], bfr2, acc2[is][ds], 0, 0, 0);
    }
  }
  #pragma unroll
  for (int is = 0; is < 2; ++is) {
    #pragma unroll
    for (int ds = 0; ds < 4; ++ds) {
      int d = dw * 64 + ds * 16 + l15;
      float bias = hb[d];
      #pragma unroll
      for (int r = 0; r < 4; ++r) {
        int i = i0 + iw * 32 + is * 16 + lg * 4 + r;
        out[((size_t)(b * N_ + i)) * D_ + d] = acc2[is][ds][r] + bias;
      }
    }
  }
}

extern "C" void kernel_launch(void* const* d_in, const int* in_sizes, int n_in,
                              void* d_out, int out_size, void* d_ws, size_t ws_size,
                              hipStream_t stream) {
  (void)in_sizes; (void)n_in; (void)out_size; (void)ws_size;
  const float* x   = (const float*)d_in[0];
  const int*   adj = (const int*)d_in[1];
  const float* W   = (const float*)d_in[2];
  const float* a   = (const float*)d_in[3];
  const float* hw  = (const float*)d_in[4];
  const float* hb  = (const float*)d_in[5];
  float* out = (float*)d_out;

  char* ws = (char*)d_ws;
  size_t off = 0;
  auto alloc = [&](size_t bytes) -> char* {
    char* p = ws + off;
    off += (bytes + 255) & ~(size_t)255;
    return p;
  };
  float* a1   = (float*)alloc(BN * 4);
  float* e1   = (float*)alloc(BN * 4);
  float* f1   = (float*)alloc(BN * 4);
  float* a2   = (float*)alloc(BN * 4);
  float* e2   = (float*)alloc(BN * 4);
  float* f2   = (float*)alloc(BN * 4);
  float* e2rs = (float*)alloc(BN * 4);
  float* f2rs = (float*)alloc(BN * 4);
  float* partA = (float*)alloc((size_t)B_ * NSEG * N_ * 4);   // 4 MB
  float* partB = (float*)alloc((size_t)B_ * NSEG * N_ * 4);   // 4 MB
  unsigned char* maskB = (unsigned char*)alloc((size_t)BN * (N_ / 8)); // 4 MB
  bf16* hT  = (bf16*)alloc((size_t)B_ * D_ * N_ * 2);   // 8 MB
  bf16* wt  = (bf16*)alloc((size_t)D_ * D_ * 2);
  bf16* hwt = (bf16*)alloc((size_t)D_ * D_ * 2);

  k_transpose_w<<<256, 256, 0, stream>>>(W, hw, wt, hwt);
  k_gemm_h<<<256, 256, 0, stream>>>(x, wt, a, hT, a1, e1, f1, a2, e2, f2);
  k_colstats<<<B_ * NSEG, 256, 0, stream>>>(adj, a1, e1, f1, a2, partA, partB, maskB);
  k_colfin<<<BN / 256, 256, 0, stream>>>(partA, partB, e2, f2, e2rs, f2rs);
  k_attmm<<<256, 512, 0, stream>>>(hT, maskB, a1, e1, f1, a2, e2rs, f2rs,
                                   hwt, hb, out);
}